// Round 4
// baseline (577.215 us; speedup 1.0000x reference)
//
#include <hip/hip_runtime.h>
#include <hip/hip_bf16.h>

#define S_LEN 2048
#define HID   4096
#define NH    32
#define NKV   8
#define HD    128
#define QKV_N 6144
#define KDIM  4096

typedef __attribute__((ext_vector_type(8))) short short8;
typedef __attribute__((ext_vector_type(4))) float floatx4;
typedef unsigned short ushort;

__device__ __forceinline__ unsigned short f2bu(float f) {
  __hip_bfloat16 b = __float2bfloat16(f);
  return *reinterpret_cast<unsigned short*>(&b);
}
__device__ __forceinline__ void store_c(float* p, float v) { *p = v; }
__device__ __forceinline__ void store_c(__hip_bfloat16* p, float v) { *p = __float2bfloat16(v); }

__device__ __forceinline__ void async_copy16(const void* g, void* l) {
  __builtin_amdgcn_global_load_lds((const __attribute__((address_space(1))) void*)g,
                                   (__attribute__((address_space(3))) void*)l, 16, 0, 0);
}

#define LGKM0  asm volatile("s_waitcnt lgkmcnt(0)" ::: "memory")
#define VMC4   asm volatile("s_waitcnt vmcnt(4)" ::: "memory")
#define VMC0   asm volatile("s_waitcnt vmcnt(0)" ::: "memory")
#define PH_BAR __builtin_amdgcn_s_barrier()

// ---------------- fused fp32 -> bf16 convert for all 5 tensors ----------------
struct bf16x4 { __hip_bfloat16 a, b, c, d; };
__global__ void cvt_all(const float* __restrict__ x,  const float* __restrict__ wq,
                        const float* __restrict__ wk, const float* __restrict__ wv,
                        const float* __restrict__ wo,
                        __hip_bfloat16* __restrict__ Xb, __hip_bfloat16* __restrict__ Wqkv,
                        __hip_bfloat16* __restrict__ Wob) {
  const int S0 = 2097152;   // x      (f4 units)
  const int S1 = 6291456;   // + wq
  const int S2 = 7340032;   // + wk
  const int S3 = 8388608;   // + wv
  const int S4 = 12582912;  // + wo
  for (int i = blockIdx.x * blockDim.x + threadIdx.x; i < S4; i += gridDim.x * blockDim.x) {
    float4 v;
    bf16x4* d;
    if (i < S0)      { v = ((const float4*)x)[i];        d = (bf16x4*)Xb + i; }
    else if (i < S1) { v = ((const float4*)wq)[i - S0];  d = (bf16x4*)Wqkv + (i - S0); }
    else if (i < S2) { v = ((const float4*)wk)[i - S1];  d = (bf16x4*)Wqkv + (i - S0); }
    else if (i < S3) { v = ((const float4*)wv)[i - S2];  d = (bf16x4*)Wqkv + (i - S0); }
    else             { v = ((const float4*)wo)[i - S3];  d = (bf16x4*)Wob + (i - S3); }
    bf16x4 o = { __float2bfloat16(v.x), __float2bfloat16(v.y),
                 __float2bfloat16(v.z), __float2bfloat16(v.w) };
    *d = o;
  }
}

// ---------------- NT bf16 GEMM, BK=64, swizzled LDS, global_load_lds staging ----------------
// (2-phase 128^2 structure; used for the out-projection where 256^2 would under-fill the grid)
template <typename CT>
__global__ __launch_bounds__(256, 2) void gemm_nt(const __hip_bfloat16* __restrict__ A,
                                                  const __hip_bfloat16* __restrict__ B,
                                                  CT* __restrict__ C, int M, int N, int K) {
  __shared__ __align__(16) ushort As[128 * 64];
  __shared__ __align__(16) ushort Bs[128 * 64];
  const int tid  = threadIdx.x;
  const int bm   = blockIdx.y * 128;
  const int bn   = blockIdx.x * 128;
  const int wave = tid >> 6;
  const int lane = tid & 63;
  const int ww   = (wave >> 1) * 64;
  const int wc   = (wave & 1) * 64;
  const int l15  = lane & 15;
  const int quad = lane >> 4;

  const ushort* Au = (const ushort*)A;
  const ushort* Bu = (const ushort*)B;

  const int rr  = lane >> 3;
  const int cc  = lane & 7;
  const int gch = cc ^ rr;
  const ushort* Ag = Au + (size_t)(bm + wave * 32 + rr) * K + gch * 8;
  const ushort* Bg = Bu + (size_t)(bn + wave * 32 + rr) * K + gch * 8;

  floatx4 acc[4][4] = {};

  for (int k0 = 0; k0 < K; k0 += 64) {
    __syncthreads();
#pragma unroll
    for (int e = 0; e < 4; ++e) {
      async_copy16(Ag + (size_t)(e * 8) * K + k0, &As[(wave * 32 + e * 8) * 64]);
      async_copy16(Bg + (size_t)(e * 8) * K + k0, &Bs[(wave * 32 + e * 8) * 64]);
    }
    __syncthreads();
#pragma unroll
    for (int kd = 0; kd < 2; ++kd) {
      short8 af[4], bf[4];
#pragma unroll
      for (int i = 0; i < 4; ++i) {
        af[i] = *(const short8*)&As[(ww + i * 16 + l15) * 64 + ((kd * 4 + quad) ^ (l15 & 7)) * 8];
        bf[i] = *(const short8*)&Bs[(wc + i * 16 + l15) * 64 + ((kd * 4 + quad) ^ (l15 & 7)) * 8];
      }
#pragma unroll
      for (int mi = 0; mi < 4; ++mi)
#pragma unroll
        for (int ni = 0; ni < 4; ++ni)
          acc[mi][ni] = __builtin_amdgcn_mfma_f32_16x16x32_bf16(af[mi], bf[ni], acc[mi][ni], 0, 0, 0);
    }
  }
#pragma unroll
  for (int mi = 0; mi < 4; ++mi)
#pragma unroll
    for (int ni = 0; ni < 4; ++ni)
#pragma unroll
      for (int r = 0; r < 4; ++r) {
        int row = bm + ww + mi * 16 + quad * 4 + r;
        int col = bn + wc + ni * 16 + l15;
        store_c(&C[(size_t)row * N + col], acc[mi][ni][r]);
      }
}

// ---------------- NT bf16 GEMM, 256^2 tile, BK=64, 8-phase deep pipeline ----------------
// 8 waves (2M x 4N), per-wave 128x64 out.  LDS 128KB: [slot][half][128x64] for A and B.
// Per phase: {ds_read subtile || stage 1 half-tile -> s_barrier -> lgkmcnt(0) ->
// setprio(1) 16xMFMA setprio(0) -> s_barrier}.  vmcnt(4) only at phases 4/8 (counted:
// exactly the 2-phases-ahead loads stay in flight); last iteration drains vmcnt(0).
__global__ __launch_bounds__(512, 2) void gemm_nt_256(const __hip_bfloat16* __restrict__ A,
                                                      const __hip_bfloat16* __restrict__ B,
                                                      __hip_bfloat16* __restrict__ C,
                                                      int M, int N, int K) {
  __shared__ __align__(16) ushort As[2][2][128 * 64];
  __shared__ __align__(16) ushort Bs[2][2][128 * 64];
  const int tid  = threadIdx.x;
  const int wv_  = tid >> 6;            // 0..7
  const int lane = tid & 63;
  const int l15  = lane & 15;
  const int quad = lane >> 4;
  const int wm   = wv_ >> 2;            // 0..1  (M half)
  const int wn   = wv_ & 3;             // 0..3  (N quarter)

  // XCD-aware bijective swizzle (gridDim.x % 8 == 0)
  const int nwg = gridDim.x;
  const int cpx = nwg >> 3;
  const int f   = (blockIdx.x & 7) * cpx + (blockIdx.x >> 3);
  const int nbx = N >> 8;
  const int bm  = (f / nbx) << 8;
  const int bn  = (f % nbx) << 8;

  const ushort* Au = (const ushort*)A;
  const ushort* Bu = (const ushort*)B;

  // stage one 128-row half-tile (16KB): 2 x global_load_lds per thread.
  // LDS [row][chunk c] holds global chunk c^(row&7)  (chunk = 8 shorts = 16B)
  auto stageA = [&](int slot, int half, int kt) {
#pragma unroll
    for (int e = 0; e < 2; ++e) {
      int n = e * 512 + wv_ * 64 + lane;
      int row = n >> 3, gc = (n & 7) ^ ((n >> 3) & 7);
      async_copy16(Au + (size_t)(bm + half * 128 + row) * K + kt * 64 + gc * 8,
                   &As[slot][half][(e * 512 + wv_ * 64) * 8]);
    }
  };
  auto stageB = [&](int slot, int half, int kt) {
#pragma unroll
    for (int e = 0; e < 2; ++e) {
      int n = e * 512 + wv_ * 64 + lane;
      int row = n >> 3, gc = (n & 7) ^ ((n >> 3) & 7);
      async_copy16(Bu + (size_t)(bn + half * 128 + row) * K + kt * 64 + gc * 8,
                   &Bs[slot][half][(e * 512 + wv_ * 64) * 8]);
    }
  };

  floatx4 acc[8][4] = {};
  short8 a[4][2], b[4][2];

#define LDA(SLOT, I0)                                                                       \
  {                                                                                         \
    _Pragma("unroll") for (int ii = 0; ii < 4; ++ii) _Pragma("unroll") for (int kd = 0; kd < 2; ++kd) \
        a[ii][kd] = *(const short8*)&As[SLOT][wm][((I0) * 16 + ii * 16 + l15) * 64 +        \
                                                  (((kd * 4 + quad) ^ (l15 & 7)) * 8)];     \
  }
#define LDB(SLOT, J0)                                                                       \
  {                                                                                         \
    _Pragma("unroll") for (int jj = 0; jj < 2; ++jj) _Pragma("unroll") for (int kd = 0; kd < 2; ++kd) \
        b[(J0) + jj][kd] = *(const short8*)&Bs[SLOT][wn >> 1][((wn & 1) * 64 + ((J0) + jj) * 16 + l15) * 64 + \
                                                              (((kd * 4 + quad) ^ (l15 & 7)) * 8)]; \
  }
#define MM(IA, JB)                                                                          \
  {                                                                                         \
    __builtin_amdgcn_s_setprio(1);                                                          \
    _Pragma("unroll") for (int ii = 0; ii < 4; ++ii)                                        \
    _Pragma("unroll") for (int jj = 0; jj < 2; ++jj)                                        \
    _Pragma("unroll") for (int kd = 0; kd < 2; ++kd)                                        \
        acc[(IA) + ii][(JB) + jj] = __builtin_amdgcn_mfma_f32_16x16x32_bf16(                \
            a[ii][kd], b[(JB) + jj][kd], acc[(IA) + ii][(JB) + jj], 0, 0, 0);               \
    __builtin_amdgcn_s_setprio(0);                                                          \
  }

  // prologue: ktile0 -> slot0 (all 4 halves), ktile1 B -> slot1
  stageA(0, 0, 0); stageA(0, 1, 0); stageB(0, 0, 0); stageB(0, 1, 0);
  stageB(1, 0, 1); stageB(1, 1, 1);
  VMC4;                                  // slot0 complete; slot1.B (4 loads) in flight
  PH_BAR;

  const int NI = K >> 7;                 // iterations of 2 K-tiles
  for (int it = 0; it < NI; ++it) {
    const int kt0 = 2 * it;
    const bool pre = (it + 1 < NI);
    // ---- phase 1: slot0, (i0-3 x j0-1)
    LDA(0, 0); LDB(0, 0);
    stageA(1, 0, kt0 + 1);
    PH_BAR; LGKM0;
    MM(0, 0);
    PH_BAR;
    // ---- phase 2: slot0, (i0-3 x j2-3)
    LDB(0, 2);
    stageA(1, 1, kt0 + 1);
    PH_BAR; LGKM0;
    MM(0, 2);
    PH_BAR;
    // ---- phase 3: slot0, (i4-7 x j0-1)
    LDA(0, 4);
    if (pre) stageB(0, 0, kt0 + 2);
    PH_BAR; LGKM0;
    MM(4, 0);
    PH_BAR;
    // ---- phase 4: slot0, (i4-7 x j2-3)
    if (pre) { stageB(0, 1, kt0 + 2); VMC4; } else { VMC0; }
    PH_BAR;
    MM(4, 2);
    PH_BAR;
    // ---- phase 5: slot1, (i0-3 x j0-1)
    LDA(1, 0); LDB(1, 0);
    if (pre) stageA(0, 0, kt0 + 2);
    PH_BAR; LGKM0;
    MM(0, 0);
    PH_BAR;
    // ---- phase 6: slot1, (i0-3 x j2-3)
    LDB(1, 2);
    if (pre) stageA(0, 1, kt0 + 2);
    PH_BAR; LGKM0;
    MM(0, 2);
    PH_BAR;
    // ---- phase 7: slot1, (i4-7 x j0-1)
    LDA(1, 4);
    if (pre) stageB(1, 0, kt0 + 3);
    PH_BAR; LGKM0;
    MM(4, 0);
    PH_BAR;
    // ---- phase 8: slot1, (i4-7 x j2-3)
    if (pre) { stageB(1, 1, kt0 + 3); VMC4; } else { VMC0; }
    PH_BAR;
    MM(4, 2);
    PH_BAR;
  }
#undef LDA
#undef LDB
#undef MM

#pragma unroll
  for (int i = 0; i < 8; ++i)
#pragma unroll
    for (int j = 0; j < 4; ++j)
#pragma unroll
      for (int r = 0; r < 4; ++r) {
        int row = bm + wm * 128 + i * 16 + quad * 4 + r;
        int col = bn + wn * 64 + j * 16 + l15;
        C[(size_t)row * N + col] = __float2bfloat16(acc[i][j][r]);
      }
}

// ---------------- RoPE for q,k -> head-major layouts (Q pre-scaled by 1/sqrt(HD)) ----------------
__global__ void rope_qk(const __hip_bfloat16* __restrict__ QKV,
                        const float* __restrict__ cosp, const float* __restrict__ sinp,
                        __hip_bfloat16* __restrict__ Qh, __hip_bfloat16* __restrict__ Kh) {
  int s = blockIdx.y;
  int col = blockIdx.x * 256 + threadIdx.x;
  if (col >= 5120) return;
  const size_t base = (size_t)s * QKV_N;
  float x = __bfloat162float(QKV[base + col]);
  int dd = col & 127;
  float val;
  if (dd < 64) {
    float xp = __bfloat162float(QKV[base + col + 64]);
    val = x * cosp[s * 64 + dd] - xp * sinp[s * 64 + dd];
  } else {
    int f = dd - 64;
    float xp = __bfloat162float(QKV[base + col - 64]);
    val = x * cosp[s * 64 + f] + xp * sinp[s * 64 + f];
  }
  if (col < HID) {
    int h = col >> 7;
    Qh[((size_t)h * S_LEN + s) * HD + dd] = __float2bfloat16(val * 0.08838834764831845f);
  } else {
    int h = (col - HID) >> 7;
    Kh[((size_t)h * S_LEN + s) * HD + dd] = __float2bfloat16(val);
  }
}

// ---------------- V transpose: QKV[s][5120+h*128+d] -> Vt[h][d][s] ----------------
__global__ void v_transpose(const __hip_bfloat16* __restrict__ QKV, __hip_bfloat16* __restrict__ Vt) {
  __shared__ ushort tile[64][130];
  int h = blockIdx.y;
  int s0 = blockIdx.x * 64;
  int t = threadIdx.x;
  const ushort* src = (const ushort*)QKV;
#pragma unroll
  for (int i = 0; i < 32; ++i) {
    int flat = i * 256 + t;
    int r = flat >> 7, c = flat & 127;
    tile[r][c] = src[(size_t)(s0 + r) * QKV_N + 5120 + h * 128 + c];
  }
  __syncthreads();
  ushort* dst = (ushort*)Vt;
#pragma unroll
  for (int i = 0; i < 8; ++i) {
    int g = i * 256 + t;
    int d = g >> 4, j4 = (g & 15) * 4;
    ushort4 o;
    o.x = tile[j4][d]; o.y = tile[j4 + 1][d]; o.z = tile[j4 + 2][d]; o.w = tile[j4 + 3][d];
    *(ushort4*)&dst[((size_t)h * HD + d) * S_LEN + s0 + j4] = o;
  }
}

// ---------------- flash attention v6 ----------------
// 2-wave blocks (128 thr), 64-row tile = 2 x 32 q-rows/wave; 1024 blocks co-resident
// at 4/CU with per-CU step-sum exactly 66 -> balanced.  Swapped QK^T, per-lane lsum,
// speculative exp + defer-max.
__global__ __launch_bounds__(128, 2) void attn(const __hip_bfloat16* __restrict__ Qh,
                                               const __hip_bfloat16* __restrict__ Kh,
                                               const __hip_bfloat16* __restrict__ Vt,
                                               __hip_bfloat16* __restrict__ AO) {
  __shared__ __align__(16) ushort Ks[64][128];    // [row][chunk c] = K chunk c^(row&15)
  __shared__ __align__(16) ushort P[2][32][72];   // [wave][q 0..31][k 0..63 +pad]
  const int bi   = blockIdx.x;                    // 0..1023
  const int g    = bi >> 8;                       // 0..3
  const int c    = bi & 255;
  const int head = c & 31;
  const int u    = c >> 5;                        // 0..7
  const int t    = (g == 0) ? (24 + u) : (g == 1) ? (16 + u)
                 : (g == 2) ? (15 - u) : (7 - u); // per-CU sums = 66 steps for all u
  const int wave = threadIdx.x >> 6;              // 0..1
  const int lane = threadIdx.x & 63;
  const int l15 = lane & 15, quad = lane >> 4;
  const int hk = head & 7;
  const int q0 = t * 64 + wave * 32;              // wave's 32 q rows
  const ushort* Qu = (const ushort*)Qh + (size_t)head * S_LEN * HD;
  const ushort* Ku = (const ushort*)Kh + (size_t)hk * S_LEN * HD;
  const ushort* Vu = (const ushort*)Vt + (size_t)hk * HD * S_LEN;

  const int rr4  = lane >> 4;
  const int cc16 = lane & 15;
  auto stage = [&](int j0) {
#pragma unroll
    for (int e = 0; e < 8; ++e) {
      int rt = (e * 4 + rr4) & 15;
      int gc = cc16 ^ rt;
      async_copy16(Ku + (size_t)(j0 + wave * 32 + e * 4 + rr4) * HD + gc * 8,
                   &Ks[wave * 32 + e * 4][0]);
    }
  };

  short8 qf[2][4];
#pragma unroll
  for (int mt = 0; mt < 2; ++mt)
#pragma unroll
    for (int kd = 0; kd < 4; ++kd)
      qf[mt][kd] = *(const short8*)(Qu + (size_t)(q0 + mt * 16 + l15) * HD + kd * 32 + quad * 8);

  floatx4 o[2][8] = {};
  float mst[2], lsum[2];
  mst[0] = mst[1] = -1e30f;
  lsum[0] = lsum[1] = 0.f;
  const int nsteps = t + 1;

  stage(0);
  for (int s = 0; s < nsteps; ++s) {
    const int j0 = s * 64;
    __syncthreads();                              // Ks ready

    floatx4 sc[2][4];
#pragma unroll
    for (int mt = 0; mt < 2; ++mt)
#pragma unroll
      for (int nt = 0; nt < 4; ++nt) sc[mt][nt] = floatx4{0.f, 0.f, 0.f, 0.f};
    __builtin_amdgcn_s_setprio(1);
#pragma unroll
    for (int nt = 0; nt < 4; ++nt) {
      short8 kf[4];
#pragma unroll
      for (int kd = 0; kd < 4; ++kd)
        kf[kd] = *(const short8*)&Ks[nt * 16 + l15][((kd * 4 + quad) ^ l15) * 8];
#pragma unroll
      for (int mt = 0; mt < 2; ++mt)
#pragma unroll
        for (int kd = 0; kd < 4; ++kd)
          sc[mt][nt] = __builtin_amdgcn_mfma_f32_16x16x32_bf16(kf[kd], qf[mt][kd], sc[mt][nt], 0, 0, 0);
    }
    __builtin_amdgcn_s_setprio(0);
    __syncthreads();                              // all waves done reading Ks
    if (s + 1 < nsteps) stage(j0 + 64);

    short8 vf0[8];
#pragma unroll
    for (int t8 = 0; t8 < 8; ++t8)
      vf0[t8] = *(const short8*)(Vu + (size_t)(t8 * 16 + l15) * S_LEN + j0 + quad * 8);

    const bool diag = (s == t);
#pragma unroll
    for (int mt = 0; mt < 2; ++mt) {
      const int qloc = wave * 32 + mt * 16 + l15;
      float pv[16];
      float vmloc = -1e30f;
#pragma unroll
      for (int nt = 0; nt < 4; ++nt)
#pragma unroll
        for (int r = 0; r < 4; ++r) {
          float x = sc[mt][nt][r];
          if (diag && (nt * 16 + quad * 4 + r > qloc)) x = -1e30f;
          pv[nt * 4 + r] = x;
          vmloc = fmaxf(vmloc, x);
        }
      float vm = fmaxf(vmloc, __shfl_xor(vmloc, 16));
      vm = fmaxf(vm, __shfl_xor(vm, 32));
      float ps = 0.f;
      ushort pk[16];
#pragma unroll
      for (int i = 0; i < 16; ++i) {
        float p = __expf(pv[i] - mst[mt]);
        ps += p;
        pk[i] = f2bu(p);
      }
      if (__any(vm > mst[mt] + 8.0f)) {
        const float mnew = fmaxf(mst[mt], vm);
        const float al = __expf(mst[mt] - mnew);
        mst[mt] = mnew;
        lsum[mt] *= al;
        ps = 0.f;
#pragma unroll
        for (int i = 0; i < 16; ++i) {
          float p = __expf(pv[i] - mst[mt]);
          ps += p;
          pk[i] = f2bu(p);
        }
        float ar[4];
#pragma unroll
        for (int r = 0; r < 4; ++r)
          ar[r] = __shfl(al, (lane & 48) | (quad * 4 + r));
#pragma unroll
        for (int t8 = 0; t8 < 8; ++t8)
#pragma unroll
          for (int r = 0; r < 4; ++r) o[mt][t8][r] *= ar[r];
      }
      lsum[mt] += ps;
#pragma unroll
      for (int nt = 0; nt < 4; ++nt) {
        ushort4 w;
        w.x = pk[nt * 4 + 0]; w.y = pk[nt * 4 + 1];
        w.z = pk[nt * 4 + 2]; w.w = pk[nt * 4 + 3];
        *(ushort4*)&P[wave][mt * 16 + l15][nt * 16 + quad * 4] = w;
      }
    }

    short8 vf1[8];
#pragma unroll
    for (int t8 = 0; t8 < 8; ++t8)
      vf1[t8] = *(const short8*)(Vu + (size_t)(t8 * 16 + l15) * S_LEN + j0 + 32 + quad * 8);

    asm volatile("s_waitcnt lgkmcnt(0)" ::: "memory");
    short8 pf[2][2];
#pragma unroll
    for (int mt = 0; mt < 2; ++mt)
#pragma unroll
      for (int hh = 0; hh < 2; ++hh)
        pf[mt][hh] = *(const short8*)&P[wave][mt * 16 + l15][hh * 32 + quad * 8];
    __builtin_amdgcn_s_setprio(1);
#pragma unroll
    for (int t8 = 0; t8 < 8; ++t8)
#pragma unroll
      for (int mt = 0; mt < 2; ++mt) {
        o[mt][t8] = __builtin_amdgcn_mfma_f32_16x16x32_bf16(pf[mt][0], vf0[t8], o[mt][t8], 0, 0, 0);
        o[mt][t8] = __builtin_amdgcn_mfma_f32_16x16x32_bf16(pf[mt][1], vf1[t8], o[mt][t8], 0, 0, 0);
      }
    __builtin_amdgcn_s_setprio(0);
  }

#pragma unroll
  for (int mt = 0; mt < 2; ++mt) {
    float ls = lsum[mt];
    ls += __shfl_xor(ls, 16);
    ls += __shfl_xor(ls, 32);
    float inv[4];
#pragma unroll
    for (int r = 0; r < 4; ++r)
      inv[r] = 1.0f / __shfl(ls, (lane & 48) | (quad * 4 + r));
#pragma unroll
    for (int r = 0; r < 4; ++r) {
      const int row = q0 + mt * 16 + quad * 4 + r;
#pragma unroll
      for (int t8 = 0; t8 < 8; ++t8)
        AO[(size_t)row * HID + head * HD + t8 * 16 + l15] = __float2bfloat16(o[mt][t8][r] * inv[r]);
    }
  }
}

extern "C" void kernel_launch(void* const* d_in, const int* in_sizes, int n_in,
                              void* d_out, int out_size, void* d_ws, size_t ws_size,
                              hipStream_t stream) {
  const float* x    = (const float*)d_in[0];
  const float* wq   = (const float*)d_in[1];
  const float* wk   = (const float*)d_in[2];
  const float* wv   = (const float*)d_in[3];
  const float* wo   = (const float*)d_in[4];
  const float* cosp = (const float*)d_in[5];
  const float* sinp = (const float*)d_in[6];
  float* out = (float*)d_out;

  char* ws = (char*)d_ws;
  size_t off = 0;
  auto alloc = [&](size_t bytes) { char* p = ws + off; off += (bytes + 255) & ~255ull; return p; };
  __hip_bfloat16* Xb   = (__hip_bfloat16*)alloc((size_t)S_LEN * KDIM * 2);
  __hip_bfloat16* Wqkv = (__hip_bfloat16*)alloc((size_t)QKV_N * KDIM * 2);
  __hip_bfloat16* Wob  = (__hip_bfloat16*)alloc((size_t)HID * HID * 2);
  __hip_bfloat16* QKVb = (__hip_bfloat16*)alloc((size_t)S_LEN * QKV_N * 2);
  __hip_bfloat16* Qh   = (__hip_bfloat16*)alloc((size_t)NH * S_LEN * HD * 2);
  __hip_bfloat16* Kh   = (__hip_bfloat16*)alloc((size_t)NKV * S_LEN * HD * 2);
  __hip_bfloat16* Vt   = (__hip_bfloat16*)alloc((size_t)NKV * HD * S_LEN * 2);
  __hip_bfloat16* AO   = (__hip_bfloat16*)alloc((size_t)S_LEN * HID * 2);

  cvt_all<<<dim3(3072), dim3(256), 0, stream>>>(x, wq, wk, wv, wo, Xb, Wqkv, Wob);

  gemm_nt_256<<<dim3((QKV_N / 256) * (S_LEN / 256)), dim3(512), 0, stream>>>(
      Xb, Wqkv, QKVb, S_LEN, QKV_N, KDIM);
  rope_qk<<<dim3(20, S_LEN), dim3(256), 0, stream>>>(QKVb, cosp, sinp, Qh, Kh);
  v_transpose<<<dim3(S_LEN / 64, NKV), dim3(256), 0, stream>>>(QKVb, Vt);
  attn<<<dim3(1024), dim3(128), 0, stream>>>(Qh, Kh, Vt, AO);
  gemm_nt<float><<<dim3(HID / 128, S_LEN / 128), dim3(256), 0, stream>>>(
      AO, Wob, out, S_LEN, HID, KDIM);
}

// Round 5
// 535.253 us; speedup vs baseline: 1.0784x; 1.0784x over previous
//
#include <hip/hip_runtime.h>
#include <hip/hip_bf16.h>

#define S_LEN 2048
#define HID   4096
#define NH    32
#define NKV   8
#define HD    128
#define QKV_N 6144
#define KDIM  4096

typedef __attribute__((ext_vector_type(8))) short short8;
typedef __attribute__((ext_vector_type(4))) float floatx4;
typedef unsigned short ushort;

__device__ __forceinline__ unsigned short f2bu(float f) {
  __hip_bfloat16 b = __float2bfloat16(f);
  return *reinterpret_cast<unsigned short*>(&b);
}
__device__ __forceinline__ void store_c(float* p, float v) { *p = v; }
__device__ __forceinline__ void store_c(__hip_bfloat16* p, float v) { *p = __float2bfloat16(v); }

__device__ __forceinline__ void async_copy16(const void* g, void* l) {
  __builtin_amdgcn_global_load_lds((const __attribute__((address_space(1))) void*)g,
                                   (__attribute__((address_space(3))) void*)l, 16, 0, 0);
}

#define LGKM0  asm volatile("s_waitcnt lgkmcnt(0)" ::: "memory")
#define VMC4   asm volatile("s_waitcnt vmcnt(4)" ::: "memory")
#define VMC0   asm volatile("s_waitcnt vmcnt(0)" ::: "memory")
#define PH_BAR __builtin_amdgcn_s_barrier()

// ---------------- fp32 -> bf16 convert ----------------
struct bf16x4 { __hip_bfloat16 a, b, c, d; };
__global__ void cvt_f32_bf16(const float* __restrict__ src, __hip_bfloat16* __restrict__ dst, int n4) {
  int i = blockIdx.x * blockDim.x + threadIdx.x;
  if (i < n4) {
    float4 v = ((const float4*)src)[i];
    bf16x4 o = { __float2bfloat16(v.x), __float2bfloat16(v.y),
                 __float2bfloat16(v.z), __float2bfloat16(v.w) };
    ((bf16x4*)dst)[i] = o;
  }
}

// ---------------- NT bf16 GEMM, BK=64, swizzled LDS, global_load_lds staging ----------------
// (2-phase 128^2 structure; used for the out-projection where 256^2 would under-fill the grid)
template <typename CT>
__global__ __launch_bounds__(256, 2) void gemm_nt(const __hip_bfloat16* __restrict__ A,
                                                  const __hip_bfloat16* __restrict__ B,
                                                  CT* __restrict__ C, int M, int N, int K) {
  __shared__ __align__(16) ushort As[128 * 64];
  __shared__ __align__(16) ushort Bs[128 * 64];
  const int tid  = threadIdx.x;
  const int bm   = blockIdx.y * 128;
  const int bn   = blockIdx.x * 128;
  const int wave = tid >> 6;
  const int lane = tid & 63;
  const int ww   = (wave >> 1) * 64;
  const int wc   = (wave & 1) * 64;
  const int l15  = lane & 15;
  const int quad = lane >> 4;

  const ushort* Au = (const ushort*)A;
  const ushort* Bu = (const ushort*)B;

  const int rr  = lane >> 3;
  const int cc  = lane & 7;
  const int gch = cc ^ rr;
  const ushort* Ag = Au + (size_t)(bm + wave * 32 + rr) * K + gch * 8;
  const ushort* Bg = Bu + (size_t)(bn + wave * 32 + rr) * K + gch * 8;

  floatx4 acc[4][4] = {};

  for (int k0 = 0; k0 < K; k0 += 64) {
    __syncthreads();
#pragma unroll
    for (int e = 0; e < 4; ++e) {
      async_copy16(Ag + (size_t)(e * 8) * K + k0, &As[(wave * 32 + e * 8) * 64]);
      async_copy16(Bg + (size_t)(e * 8) * K + k0, &Bs[(wave * 32 + e * 8) * 64]);
    }
    __syncthreads();
#pragma unroll
    for (int kd = 0; kd < 2; ++kd) {
      short8 af[4], bf[4];
#pragma unroll
      for (int i = 0; i < 4; ++i) {
        af[i] = *(const short8*)&As[(ww + i * 16 + l15) * 64 + ((kd * 4 + quad) ^ (l15 & 7)) * 8];
        bf[i] = *(const short8*)&Bs[(wc + i * 16 + l15) * 64 + ((kd * 4 + quad) ^ (l15 & 7)) * 8];
      }
#pragma unroll
      for (int mi = 0; mi < 4; ++mi)
#pragma unroll
        for (int ni = 0; ni < 4; ++ni)
          acc[mi][ni] = __builtin_amdgcn_mfma_f32_16x16x32_bf16(af[mi], bf[ni], acc[mi][ni], 0, 0, 0);
    }
  }
#pragma unroll
  for (int mi = 0; mi < 4; ++mi)
#pragma unroll
    for (int ni = 0; ni < 4; ++ni)
#pragma unroll
      for (int r = 0; r < 4; ++r) {
        int row = bm + ww + mi * 16 + quad * 4 + r;
        int col = bn + wc + ni * 16 + l15;
        store_c(&C[(size_t)row * N + col], acc[mi][ni][r]);
      }
}

// ---------------- NT bf16 GEMM, 256^2 tile, BK=64, 8-phase deep pipeline ----------------
// 8 waves (2M x 4N), per-wave 128x64 out.  LDS 128KB: [slot][half][128x64] for A and B.
// IDENTITY tile mapping: col = bid % 24 and 24 % 8 == 0 gives natural col->XCD affinity
// (each XCD's L2 holds 3 B-panels; A-slivers shared by loosely-synced blocks).
// Per phase: {ds_read subtile || stage 1 half-tile -> s_barrier -> lgkmcnt(0) ->
// setprio(1) 16xMFMA setprio(0) -> s_barrier}.  vmcnt(4) only at phases 4/8.
__global__ __launch_bounds__(512, 2) void gemm_nt_256(const __hip_bfloat16* __restrict__ A,
                                                      const __hip_bfloat16* __restrict__ B,
                                                      __hip_bfloat16* __restrict__ C,
                                                      int M, int N, int K) {
  __shared__ __align__(16) ushort As[2][2][128 * 64];
  __shared__ __align__(16) ushort Bs[2][2][128 * 64];
  const int tid  = threadIdx.x;
  const int wv_  = tid >> 6;            // 0..7
  const int lane = tid & 63;
  const int l15  = lane & 15;
  const int quad = lane >> 4;
  const int wm   = wv_ >> 2;            // 0..1  (M half)
  const int wn   = wv_ & 3;             // 0..3  (N quarter)

  const int nbx = N >> 8;               // 24 column tiles (== 0 mod 8)
  const int bm  = (blockIdx.x / nbx) << 8;
  const int bn  = (blockIdx.x % nbx) << 8;

  const ushort* Au = (const ushort*)A;
  const ushort* Bu = (const ushort*)B;

  // stage one 128-row half-tile (16KB): 2 x global_load_lds per thread.
  // LDS [row][chunk c] holds global chunk c^(row&7)  (chunk = 8 shorts = 16B)
  auto stageA = [&](int slot, int half, int kt) {
#pragma unroll
    for (int e = 0; e < 2; ++e) {
      int n = e * 512 + wv_ * 64 + lane;
      int row = n >> 3, gc = (n & 7) ^ ((n >> 3) & 7);
      async_copy16(Au + (size_t)(bm + half * 128 + row) * K + kt * 64 + gc * 8,
                   &As[slot][half][(e * 512 + wv_ * 64) * 8]);
    }
  };
  auto stageB = [&](int slot, int half, int kt) {
#pragma unroll
    for (int e = 0; e < 2; ++e) {
      int n = e * 512 + wv_ * 64 + lane;
      int row = n >> 3, gc = (n & 7) ^ ((n >> 3) & 7);
      async_copy16(Bu + (size_t)(bn + half * 128 + row) * K + kt * 64 + gc * 8,
                   &Bs[slot][half][(e * 512 + wv_ * 64) * 8]);
    }
  };

  floatx4 acc[8][4] = {};
  short8 a[4][2], b[4][2];

#define LDA(SLOT, I0)                                                                       \
  {                                                                                         \
    _Pragma("unroll") for (int ii = 0; ii < 4; ++ii) _Pragma("unroll") for (int kd = 0; kd < 2; ++kd) \
        a[ii][kd] = *(const short8*)&As[SLOT][wm][((I0) * 16 + ii * 16 + l15) * 64 +        \
                                                  (((kd * 4 + quad) ^ (l15 & 7)) * 8)];     \
  }
#define LDB(SLOT, J0)                                                                       \
  {                                                                                         \
    _Pragma("unroll") for (int jj = 0; jj < 2; ++jj) _Pragma("unroll") for (int kd = 0; kd < 2; ++kd) \
        b[(J0) + jj][kd] = *(const short8*)&Bs[SLOT][wn >> 1][((wn & 1) * 64 + ((J0) + jj) * 16 + l15) * 64 + \
                                                              (((kd * 4 + quad) ^ (l15 & 7)) * 8)]; \
  }
#define MM(IA, JB)                                                                          \
  {                                                                                         \
    __builtin_amdgcn_s_setprio(1);                                                          \
    _Pragma("unroll") for (int ii = 0; ii < 4; ++ii)                                        \
    _Pragma("unroll") for (int jj = 0; jj < 2; ++jj)                                        \
    _Pragma("unroll") for (int kd = 0; kd < 2; ++kd)                                        \
        acc[(IA) + ii][(JB) + jj] = __builtin_amdgcn_mfma_f32_16x16x32_bf16(                \
            a[ii][kd], b[(JB) + jj][kd], acc[(IA) + ii][(JB) + jj], 0, 0, 0);               \
    __builtin_amdgcn_s_setprio(0);                                                          \
  }

  // prologue: ktile0 -> slot0 (all 4 halves), ktile1 B -> slot1
  stageA(0, 0, 0); stageA(0, 1, 0); stageB(0, 0, 0); stageB(0, 1, 0);
  stageB(1, 0, 1); stageB(1, 1, 1);
  VMC4;                                  // slot0 complete; slot1.B (4 loads) in flight
  PH_BAR;

  const int NI = K >> 7;                 // iterations of 2 K-tiles
  for (int it = 0; it < NI; ++it) {
    const int kt0 = 2 * it;
    const bool pre = (it + 1 < NI);
    // ---- phase 1: slot0, (i0-3 x j0-1)
    LDA(0, 0); LDB(0, 0);
    stageA(1, 0, kt0 + 1);
    PH_BAR; LGKM0;
    MM(0, 0);
    PH_BAR;
    // ---- phase 2: slot0, (i0-3 x j2-3)
    LDB(0, 2);
    stageA(1, 1, kt0 + 1);
    PH_BAR; LGKM0;
    MM(0, 2);
    PH_BAR;
    // ---- phase 3: slot0, (i4-7 x j0-1)
    LDA(0, 4);
    if (pre) stageB(0, 0, kt0 + 2);
    PH_BAR; LGKM0;
    MM(4, 0);
    PH_BAR;
    // ---- phase 4: slot0, (i4-7 x j2-3)
    if (pre) { stageB(0, 1, kt0 + 2); VMC4; } else { VMC0; }
    PH_BAR;
    MM(4, 2);
    PH_BAR;
    // ---- phase 5: slot1, (i0-3 x j0-1)
    LDA(1, 0); LDB(1, 0);
    if (pre) stageA(0, 0, kt0 + 2);
    PH_BAR; LGKM0;
    MM(0, 0);
    PH_BAR;
    // ---- phase 6: slot1, (i0-3 x j2-3)
    LDB(1, 2);
    if (pre) stageA(0, 1, kt0 + 2);
    PH_BAR; LGKM0;
    MM(0, 2);
    PH_BAR;
    // ---- phase 7: slot1, (i4-7 x j0-1)
    LDA(1, 4);
    if (pre) stageB(1, 0, kt0 + 3);
    PH_BAR; LGKM0;
    MM(4, 0);
    PH_BAR;
    // ---- phase 8: slot1, (i4-7 x j2-3)
    if (pre) { stageB(1, 1, kt0 + 3); VMC4; } else { VMC0; }
    PH_BAR;
    MM(4, 2);
    PH_BAR;
  }
#undef LDA
#undef LDB
#undef MM

#pragma unroll
  for (int i = 0; i < 8; ++i)
#pragma unroll
    for (int j = 0; j < 4; ++j)
#pragma unroll
      for (int r = 0; r < 4; ++r) {
        int row = bm + wm * 128 + i * 16 + quad * 4 + r;
        int col = bn + wn * 64 + j * 16 + l15;
        C[(size_t)row * N + col] = __float2bfloat16(acc[i][j][r]);
      }
}

// ---------------- RoPE for q,k -> head-major layouts (Q pre-scaled by 1/sqrt(HD)) ----------------
__global__ void rope_qk(const __hip_bfloat16* __restrict__ QKV,
                        const float* __restrict__ cosp, const float* __restrict__ sinp,
                        __hip_bfloat16* __restrict__ Qh, __hip_bfloat16* __restrict__ Kh) {
  int s = blockIdx.y;
  int col = blockIdx.x * 256 + threadIdx.x;
  if (col >= 5120) return;
  const size_t base = (size_t)s * QKV_N;
  float x = __bfloat162float(QKV[base + col]);
  int dd = col & 127;
  float val;
  if (dd < 64) {
    float xp = __bfloat162float(QKV[base + col + 64]);
    val = x * cosp[s * 64 + dd] - xp * sinp[s * 64 + dd];
  } else {
    int f = dd - 64;
    float xp = __bfloat162float(QKV[base + col - 64]);
    val = x * cosp[s * 64 + f] + xp * sinp[s * 64 + f];
  }
  if (col < HID) {
    int h = col >> 7;
    Qh[((size_t)h * S_LEN + s) * HD + dd] = __float2bfloat16(val * 0.08838834764831845f);
  } else {
    int h = (col - HID) >> 7;
    Kh[((size_t)h * S_LEN + s) * HD + dd] = __float2bfloat16(val);
  }
}

// ---------------- V transpose: QKV[s][5120+h*128+d] -> Vt[h][d][s] ----------------
__global__ void v_transpose(const __hip_bfloat16* __restrict__ QKV, __hip_bfloat16* __restrict__ Vt) {
  __shared__ ushort tile[64][130];
  int h = blockIdx.y;
  int s0 = blockIdx.x * 64;
  int t = threadIdx.x;
  const ushort* src = (const ushort*)QKV;
#pragma unroll
  for (int i = 0; i < 32; ++i) {
    int flat = i * 256 + t;
    int r = flat >> 7, c = flat & 127;
    tile[r][c] = src[(size_t)(s0 + r) * QKV_N + 5120 + h * 128 + c];
  }
  __syncthreads();
  ushort* dst = (ushort*)Vt;
#pragma unroll
  for (int i = 0; i < 8; ++i) {
    int g = i * 256 + t;
    int d = g >> 4, j4 = (g & 15) * 4;
    ushort4 o;
    o.x = tile[j4][d]; o.y = tile[j4 + 1][d]; o.z = tile[j4 + 2][d]; o.w = tile[j4 + 3][d];
    *(ushort4*)&dst[((size_t)h * HD + d) * S_LEN + s0 + j4] = o;
  }
}

// ---------------- flash attention v6 ----------------
// 2-wave blocks (128 thr), 64-row tile = 2 x 32 q-rows/wave; 1024 blocks co-resident
// at 4/CU with per-CU step-sum exactly 66 -> balanced.  Swapped QK^T, per-lane lsum,
// speculative exp + defer-max.
__global__ __launch_bounds__(128, 2) void attn(const __hip_bfloat16* __restrict__ Qh,
                                               const __hip_bfloat16* __restrict__ Kh,
                                               const __hip_bfloat16* __restrict__ Vt,
                                               __hip_bfloat16* __restrict__ AO) {
  __shared__ __align__(16) ushort Ks[64][128];    // [row][chunk c] = K chunk c^(row&15)
  __shared__ __align__(16) ushort P[2][32][72];   // [wave][q 0..31][k 0..63 +pad]
  const int bi   = blockIdx.x;                    // 0..1023
  const int g    = bi >> 8;                       // 0..3
  const int c    = bi & 255;
  const int head = c & 31;
  const int u    = c >> 5;                        // 0..7
  const int t    = (g == 0) ? (24 + u) : (g == 1) ? (16 + u)
                 : (g == 2) ? (15 - u) : (7 - u); // per-CU sums = 66 steps for all u
  const int wave = threadIdx.x >> 6;              // 0..1
  const int lane = threadIdx.x & 63;
  const int l15 = lane & 15, quad = lane >> 4;
  const int hk = head & 7;
  const int q0 = t * 64 + wave * 32;              // wave's 32 q rows
  const ushort* Qu = (const ushort*)Qh + (size_t)head * S_LEN * HD;
  const ushort* Ku = (const ushort*)Kh + (size_t)hk * S_LEN * HD;
  const ushort* Vu = (const ushort*)Vt + (size_t)hk * HD * S_LEN;

  const int rr4  = lane >> 4;
  const int cc16 = lane & 15;
  auto stage = [&](int j0) {
#pragma unroll
    for (int e = 0; e < 8; ++e) {
      int rt = (e * 4 + rr4) & 15;
      int gc = cc16 ^ rt;
      async_copy16(Ku + (size_t)(j0 + wave * 32 + e * 4 + rr4) * HD + gc * 8,
                   &Ks[wave * 32 + e * 4][0]);
    }
  };

  short8 qf[2][4];
#pragma unroll
  for (int mt = 0; mt < 2; ++mt)
#pragma unroll
    for (int kd = 0; kd < 4; ++kd)
      qf[mt][kd] = *(const short8*)(Qu + (size_t)(q0 + mt * 16 + l15) * HD + kd * 32 + quad * 8);

  floatx4 o[2][8] = {};
  float mst[2], lsum[2];
  mst[0] = mst[1] = -1e30f;
  lsum[0] = lsum[1] = 0.f;
  const int nsteps = t + 1;

  stage(0);
  for (int s = 0; s < nsteps; ++s) {
    const int j0 = s * 64;
    __syncthreads();                              // Ks ready

    floatx4 sc[2][4];
#pragma unroll
    for (int mt = 0; mt < 2; ++mt)
#pragma unroll
      for (int nt = 0; nt < 4; ++nt) sc[mt][nt] = floatx4{0.f, 0.f, 0.f, 0.f};
    __builtin_amdgcn_s_setprio(1);
#pragma unroll
    for (int nt = 0; nt < 4; ++nt) {
      short8 kf[4];
#pragma unroll
      for (int kd = 0; kd < 4; ++kd)
        kf[kd] = *(const short8*)&Ks[nt * 16 + l15][((kd * 4 + quad) ^ l15) * 8];
#pragma unroll
      for (int mt = 0; mt < 2; ++mt)
#pragma unroll
        for (int kd = 0; kd < 4; ++kd)
          sc[mt][nt] = __builtin_amdgcn_mfma_f32_16x16x32_bf16(kf[kd], qf[mt][kd], sc[mt][nt], 0, 0, 0);
    }
    __builtin_amdgcn_s_setprio(0);
    __syncthreads();                              // all waves done reading Ks
    if (s + 1 < nsteps) stage(j0 + 64);

    short8 vf0[8];
#pragma unroll
    for (int t8 = 0; t8 < 8; ++t8)
      vf0[t8] = *(const short8*)(Vu + (size_t)(t8 * 16 + l15) * S_LEN + j0 + quad * 8);

    const bool diag = (s == t);
#pragma unroll
    for (int mt = 0; mt < 2; ++mt) {
      const int qloc = wave * 32 + mt * 16 + l15;
      float pv[16];
      float vmloc = -1e30f;
#pragma unroll
      for (int nt = 0; nt < 4; ++nt)
#pragma unroll
        for (int r = 0; r < 4; ++r) {
          float x = sc[mt][nt][r];
          if (diag && (nt * 16 + quad * 4 + r > qloc)) x = -1e30f;
          pv[nt * 4 + r] = x;
          vmloc = fmaxf(vmloc, x);
        }
      float vm = fmaxf(vmloc, __shfl_xor(vmloc, 16));
      vm = fmaxf(vm, __shfl_xor(vm, 32));
      float ps = 0.f;
      ushort pk[16];
#pragma unroll
      for (int i = 0; i < 16; ++i) {
        float p = __expf(pv[i] - mst[mt]);
        ps += p;
        pk[i] = f2bu(p);
      }
      if (__any(vm > mst[mt] + 8.0f)) {
        const float mnew = fmaxf(mst[mt], vm);
        const float al = __expf(mst[mt] - mnew);
        mst[mt] = mnew;
        lsum[mt] *= al;
        ps = 0.f;
#pragma unroll
        for (int i = 0; i < 16; ++i) {
          float p = __expf(pv[i] - mst[mt]);
          ps += p;
          pk[i] = f2bu(p);
        }
        float ar[4];
#pragma unroll
        for (int r = 0; r < 4; ++r)
          ar[r] = __shfl(al, (lane & 48) | (quad * 4 + r));
#pragma unroll
        for (int t8 = 0; t8 < 8; ++t8)
#pragma unroll
          for (int r = 0; r < 4; ++r) o[mt][t8][r] *= ar[r];
      }
      lsum[mt] += ps;
#pragma unroll
      for (int nt = 0; nt < 4; ++nt) {
        ushort4 w;
        w.x = pk[nt * 4 + 0]; w.y = pk[nt * 4 + 1];
        w.z = pk[nt * 4 + 2]; w.w = pk[nt * 4 + 3];
        *(ushort4*)&P[wave][mt * 16 + l15][nt * 16 + quad * 4] = w;
      }
    }

    short8 vf1[8];
#pragma unroll
    for (int t8 = 0; t8 < 8; ++t8)
      vf1[t8] = *(const short8*)(Vu + (size_t)(t8 * 16 + l15) * S_LEN + j0 + 32 + quad * 8);

    asm volatile("s_waitcnt lgkmcnt(0)" ::: "memory");
    short8 pf[2][2];
#pragma unroll
    for (int mt = 0; mt < 2; ++mt)
#pragma unroll
      for (int hh = 0; hh < 2; ++hh)
        pf[mt][hh] = *(const short8*)&P[wave][mt * 16 + l15][hh * 32 + quad * 8];
    __builtin_amdgcn_s_setprio(1);
#pragma unroll
    for (int t8 = 0; t8 < 8; ++t8)
#pragma unroll
      for (int mt = 0; mt < 2; ++mt) {
        o[mt][t8] = __builtin_amdgcn_mfma_f32_16x16x32_bf16(pf[mt][0], vf0[t8], o[mt][t8], 0, 0, 0);
        o[mt][t8] = __builtin_amdgcn_mfma_f32_16x16x32_bf16(pf[mt][1], vf1[t8], o[mt][t8], 0, 0, 0);
      }
    __builtin_amdgcn_s_setprio(0);
  }

#pragma unroll
  for (int mt = 0; mt < 2; ++mt) {
    float ls = lsum[mt];
    ls += __shfl_xor(ls, 16);
    ls += __shfl_xor(ls, 32);
    float inv[4];
#pragma unroll
    for (int r = 0; r < 4; ++r)
      inv[r] = 1.0f / __shfl(ls, (lane & 48) | (quad * 4 + r));
#pragma unroll
    for (int r = 0; r < 4; ++r) {
      const int row = q0 + mt * 16 + quad * 4 + r;
#pragma unroll
      for (int t8 = 0; t8 < 8; ++t8)
        AO[(size_t)row * HID + head * HD + t8 * 16 + l15] = __float2bfloat16(o[mt][t8][r] * inv[r]);
    }
  }
}

extern "C" void kernel_launch(void* const* d_in, const int* in_sizes, int n_in,
                              void* d_out, int out_size, void* d_ws, size_t ws_size,
                              hipStream_t stream) {
  const float* x    = (const float*)d_in[0];
  const float* wq   = (const float*)d_in[1];
  const float* wk   = (const float*)d_in[2];
  const float* wv   = (const float*)d_in[3];
  const float* wo   = (const float*)d_in[4];
  const float* cosp = (const float*)d_in[5];
  const float* sinp = (const float*)d_in[6];
  float* out = (float*)d_out;

  char* ws = (char*)d_ws;
  size_t off = 0;
  auto alloc = [&](size_t bytes) { char* p = ws + off; off += (bytes + 255) & ~255ull; return p; };
  __hip_bfloat16* Xb   = (__hip_bfloat16*)alloc((size_t)S_LEN * KDIM * 2);
  __hip_bfloat16* Wqkv = (__hip_bfloat16*)alloc((size_t)QKV_N * KDIM * 2);
  __hip_bfloat16* Wob  = (__hip_bfloat16*)alloc((size_t)HID * HID * 2);
  __hip_bfloat16* QKVb = (__hip_bfloat16*)alloc((size_t)S_LEN * QKV_N * 2);
  __hip_bfloat16* Qh   = (__hip_bfloat16*)alloc((size_t)NH * S_LEN * HD * 2);
  __hip_bfloat16* Kh   = (__hip_bfloat16*)alloc((size_t)NKV * S_LEN * HD * 2);
  __hip_bfloat16* Vt   = (__hip_bfloat16*)alloc((size_t)NKV * HD * S_LEN * 2);
  __hip_bfloat16* AO   = (__hip_bfloat16*)alloc((size_t)S_LEN * HID * 2);

  auto cvt = [&](const float* s, __hip_bfloat16* dpt, size_t n) {
    int n4 = (int)(n / 4);
    cvt_f32_bf16<<<dim3((n4 + 255) / 256), dim3(256), 0, stream>>>(s, dpt, n4);
  };
  cvt(x, Xb, (size_t)S_LEN * KDIM);
  cvt(wq, Wqkv, (size_t)HID * KDIM);
  cvt(wk, Wqkv + (size_t)HID * KDIM, (size_t)NKV * HD * KDIM);
  cvt(wv, Wqkv + (size_t)(HID + NKV * HD) * KDIM, (size_t)NKV * HD * KDIM);
  cvt(wo, Wob, (size_t)HID * HID);

  gemm_nt_256<<<dim3((QKV_N / 256) * (S_LEN / 256)), dim3(512), 0, stream>>>(
      Xb, Wqkv, QKVb, S_LEN, QKV_N, KDIM);
  rope_qk<<<dim3(20, S_LEN), dim3(256), 0, stream>>>(QKVb, cosp, sinp, Qh, Kh);
  v_transpose<<<dim3(S_LEN / 64, NKV), dim3(256), 0, stream>>>(QKVb, Vt);
  attn<<<dim3(1024), dim3(128), 0, stream>>>(Qh, Kh, Vt, AO);
  gemm_nt<float><<<dim3(HID / 128, S_LEN / 128), dim3(256), 0, stream>>>(
      AO, Wob, out, S_LEN, HID, KDIM);
}

// Round 6
// 515.229 us; speedup vs baseline: 1.1203x; 1.0389x over previous
//
#include <hip/hip_runtime.h>
#include <hip/hip_bf16.h>
#include <type_traits>

#define S_LEN 2048
#define HID   4096
#define NH    32
#define NKV   8
#define HD    128
#define QKV_N 6144
#define KDIM  4096

typedef __attribute__((ext_vector_type(8))) short short8;
typedef __attribute__((ext_vector_type(4))) float floatx4;
typedef unsigned short ushort;

__device__ __forceinline__ unsigned short f2bu(float f) {
  __hip_bfloat16 b = __float2bfloat16(f);
  return *reinterpret_cast<unsigned short*>(&b);
}
__device__ __forceinline__ float bu2f(ushort u) {
  return __bfloat162float(*reinterpret_cast<__hip_bfloat16*>(&u));
}
__device__ __forceinline__ void store_c(float* p, float v) { *p = v; }
__device__ __forceinline__ void store_c(__hip_bfloat16* p, float v) { *p = __float2bfloat16(v); }

__device__ __forceinline__ void async_copy16(const void* g, void* l) {
  __builtin_amdgcn_global_load_lds((const __attribute__((address_space(1))) void*)g,
                                   (__attribute__((address_space(3))) void*)l, 16, 0, 0);
}

// ---------------- fused fp32 -> bf16 convert for all 5 tensors ----------------
struct bf16x4 { __hip_bfloat16 a, b, c, d; };
__global__ void cvt_all(const float* __restrict__ x,  const float* __restrict__ wq,
                        const float* __restrict__ wk, const float* __restrict__ wv,
                        const float* __restrict__ wo,
                        __hip_bfloat16* __restrict__ Xb, __hip_bfloat16* __restrict__ Wqkv,
                        __hip_bfloat16* __restrict__ Wob) {
  const int S0 = 2097152;   // x      (float4 units)
  const int S1 = 6291456;   // + wq
  const int S2 = 7340032;   // + wk
  const int S3 = 8388608;   // + wv
  const int S4 = 12582912;  // + wo
  for (int i = blockIdx.x * blockDim.x + threadIdx.x; i < S4; i += gridDim.x * blockDim.x) {
    float4 v;
    bf16x4* d;
    if (i < S0)      { v = ((const float4*)x)[i];        d = (bf16x4*)Xb + i; }
    else if (i < S1) { v = ((const float4*)wq)[i - S0];  d = (bf16x4*)Wqkv + (i - S0); }
    else if (i < S2) { v = ((const float4*)wk)[i - S1];  d = (bf16x4*)Wqkv + (i - S0); }
    else if (i < S3) { v = ((const float4*)wv)[i - S2];  d = (bf16x4*)Wqkv + (i - S0); }
    else             { v = ((const float4*)wo)[i - S3];  d = (bf16x4*)Wob + (i - S3); }
    bf16x4 o = { __float2bfloat16(v.x), __float2bfloat16(v.y),
                 __float2bfloat16(v.z), __float2bfloat16(v.w) };
    *d = o;
  }
}

// ---------------- NT bf16 GEMM, 128^2, BK=64, swizzled LDS, global_load_lds staging ----------------
// C[M][N] = sum_k A[m][k]*B[n][k].  LDS[row][chunk c] holds global chunk c^(row&7) (chunk=8 shorts).
template <typename CT>
__global__ __launch_bounds__(256, 2) void gemm_nt(const __hip_bfloat16* __restrict__ A,
                                                  const __hip_bfloat16* __restrict__ B,
                                                  CT* __restrict__ C, int M, int N, int K) {
  __shared__ __align__(16) ushort As[128 * 64];
  __shared__ __align__(16) ushort Bs[128 * 64];
  const int tid  = threadIdx.x;
  const int bm   = blockIdx.y * 128;
  const int bn   = blockIdx.x * 128;
  const int wave = tid >> 6;
  const int lane = tid & 63;
  const int ww   = (wave >> 1) * 64;
  const int wc   = (wave & 1) * 64;
  const int l15  = lane & 15;
  const int quad = lane >> 4;

  const ushort* Au = (const ushort*)A;
  const ushort* Bu = (const ushort*)B;

  const int rr  = lane >> 3;
  const int cc  = lane & 7;
  const int gch = cc ^ rr;
  const ushort* Ag = Au + (size_t)(bm + wave * 32 + rr) * K + gch * 8;
  const ushort* Bg = Bu + (size_t)(bn + wave * 32 + rr) * K + gch * 8;

  floatx4 acc[4][4] = {};

  for (int k0 = 0; k0 < K; k0 += 64) {
    __syncthreads();
#pragma unroll
    for (int e = 0; e < 4; ++e) {
      async_copy16(Ag + (size_t)(e * 8) * K + k0, &As[(wave * 32 + e * 8) * 64]);
      async_copy16(Bg + (size_t)(e * 8) * K + k0, &Bs[(wave * 32 + e * 8) * 64]);
    }
    __syncthreads();
#pragma unroll
    for (int kd = 0; kd < 2; ++kd) {
      short8 af[4], bf[4];
#pragma unroll
      for (int i = 0; i < 4; ++i) {
        af[i] = *(const short8*)&As[(ww + i * 16 + l15) * 64 + ((kd * 4 + quad) ^ (l15 & 7)) * 8];
        bf[i] = *(const short8*)&Bs[(wc + i * 16 + l15) * 64 + ((kd * 4 + quad) ^ (l15 & 7)) * 8];
      }
#pragma unroll
      for (int mi = 0; mi < 4; ++mi)
#pragma unroll
        for (int ni = 0; ni < 4; ++ni)
          acc[mi][ni] = __builtin_amdgcn_mfma_f32_16x16x32_bf16(af[mi], bf[ni], acc[mi][ni], 0, 0, 0);
    }
  }
#pragma unroll
  for (int mi = 0; mi < 4; ++mi)
#pragma unroll
    for (int ni = 0; ni < 4; ++ni)
#pragma unroll
      for (int r = 0; r < 4; ++r) {
        int row = bm + ww + mi * 16 + quad * 4 + r;
        int col = bn + wc + ni * 16 + l15;
        store_c(&C[(size_t)row * N + col], acc[mi][ni][r]);
      }
}

// ---------------- RoPE for q,k -> head-major layouts, vectorized short8 ----------------
// One thread = one (seq row, rope-head, 8-wide d-octet): 2 short8 loads, 2 short8 stores.
// Q pre-scaled by 1/sqrt(HD).  40 rope-heads = 32 q + 8 k (col = head*128 works for both).
__global__ void rope_qk(const __hip_bfloat16* __restrict__ QKV,
                        const float* __restrict__ cosp, const float* __restrict__ sinp,
                        __hip_bfloat16* __restrict__ Qh, __hip_bfloat16* __restrict__ Kh) {
  const int idx  = blockIdx.x * 256 + threadIdx.x;   // 0 .. 2048*40*8-1
  const int oct  = idx & 7;
  const int rh   = idx >> 3;
  const int head = rh % 40;
  const int s    = rh / 40;

  const ushort* src = (const ushort*)QKV + (size_t)s * QKV_N + head * 128 + oct * 8;
  short8 x1 = *(const short8*)src;         // d in [oct*8, oct*8+8)
  short8 x2 = *(const short8*)(src + 64);  // d+64
  float4 c0 = *(const float4*)&cosp[s * 64 + oct * 8];
  float4 c1 = *(const float4*)&cosp[s * 64 + oct * 8 + 4];
  float4 sn0 = *(const float4*)&sinp[s * 64 + oct * 8];
  float4 sn1 = *(const float4*)&sinp[s * 64 + oct * 8 + 4];
  float cf[8] = {c0.x, c0.y, c0.z, c0.w, c1.x, c1.y, c1.z, c1.w};
  float sf[8] = {sn0.x, sn0.y, sn0.z, sn0.w, sn1.x, sn1.y, sn1.z, sn1.w};

  const float scale = (head < 32) ? 0.08838834764831845f : 1.0f;
  short8 o1, o2;
#pragma unroll
  for (int j = 0; j < 8; ++j) {
    float a = bu2f((ushort)x1[j]);
    float b = bu2f((ushort)x2[j]);
    o1[j] = (short)f2bu((a * cf[j] - b * sf[j]) * scale);
    o2[j] = (short)f2bu((b * cf[j] + a * sf[j]) * scale);
  }
  ushort* dst = (head < 32)
      ? (ushort*)Qh + ((size_t)head * S_LEN + s) * HD + oct * 8
      : (ushort*)Kh + ((size_t)(head - 32) * S_LEN + s) * HD + oct * 8;
  *(short8*)dst = o1;
  *(short8*)(dst + 64) = o2;
}

// ---------------- V transpose: QKV[s][5120+h*128+d] -> Vt[h][d][s] ----------------
__global__ void v_transpose(const __hip_bfloat16* __restrict__ QKV, __hip_bfloat16* __restrict__ Vt) {
  __shared__ ushort tile[64][130];
  int h = blockIdx.y;
  int s0 = blockIdx.x * 64;
  int t = threadIdx.x;
  const ushort* src = (const ushort*)QKV;
#pragma unroll
  for (int i = 0; i < 32; ++i) {
    int flat = i * 256 + t;
    int r = flat >> 7, c = flat & 127;
    tile[r][c] = src[(size_t)(s0 + r) * QKV_N + 5120 + h * 128 + c];
  }
  __syncthreads();
  ushort* dst = (ushort*)Vt;
#pragma unroll
  for (int i = 0; i < 8; ++i) {
    int g = i * 256 + t;
    int d = g >> 4, j4 = (g & 15) * 4;
    ushort4 o;
    o.x = tile[j4][d]; o.y = tile[j4 + 1][d]; o.z = tile[j4 + 2][d]; o.w = tile[j4 + 3][d];
    *(ushort4*)&dst[((size_t)h * HD + d) * S_LEN + s0 + j4] = o;
  }
}

// ---------------- flash attention v7 ----------------
// v6 structure (2-wave blocks, 64-row tile, 1024 blocks balanced 4/CU) with:
// - mask code only on the diagonal step (compile-time split)
// - defer-max predicate from per-lane local max (__any ballots all 64 lanes);
//   cross-quad max reduce moved inside the rare rescale branch.
__global__ __launch_bounds__(128, 2) void attn(const __hip_bfloat16* __restrict__ Qh,
                                               const __hip_bfloat16* __restrict__ Kh,
                                               const __hip_bfloat16* __restrict__ Vt,
                                               __hip_bfloat16* __restrict__ AO) {
  __shared__ __align__(16) ushort Ks[64][128];    // [row][chunk c] = K chunk c^(row&15)
  __shared__ __align__(16) ushort P[2][32][72];   // [wave][q 0..31][k 0..63 +pad]
  const int bi   = blockIdx.x;                    // 0..1023
  const int g    = bi >> 8;                       // 0..3
  const int c    = bi & 255;
  const int head = c & 31;
  const int u    = c >> 5;                        // 0..7
  const int t    = (g == 0) ? (24 + u) : (g == 1) ? (16 + u)
                 : (g == 2) ? (15 - u) : (7 - u); // per-CU sums = 66 steps for all u
  const int wave = threadIdx.x >> 6;              // 0..1
  const int lane = threadIdx.x & 63;
  const int l15 = lane & 15, quad = lane >> 4;
  const int hk = head & 7;
  const int q0 = t * 64 + wave * 32;              // wave's 32 q rows
  const ushort* Qu = (const ushort*)Qh + (size_t)head * S_LEN * HD;
  const ushort* Ku = (const ushort*)Kh + (size_t)hk * S_LEN * HD;
  const ushort* Vu = (const ushort*)Vt + (size_t)hk * HD * S_LEN;

  const int rr4  = lane >> 4;
  const int cc16 = lane & 15;
  auto stage = [&](int j0) {
#pragma unroll
    for (int e = 0; e < 8; ++e) {
      int rt = (e * 4 + rr4) & 15;
      int gc = cc16 ^ rt;
      async_copy16(Ku + (size_t)(j0 + wave * 32 + e * 4 + rr4) * HD + gc * 8,
                   &Ks[wave * 32 + e * 4][0]);
    }
  };

  short8 qf[2][4];
#pragma unroll
  for (int mt = 0; mt < 2; ++mt)
#pragma unroll
    for (int kd = 0; kd < 4; ++kd)
      qf[mt][kd] = *(const short8*)(Qu + (size_t)(q0 + mt * 16 + l15) * HD + kd * 32 + quad * 8);

  floatx4 o[2][8] = {};
  float mst[2], lsum[2];
  mst[0] = mst[1] = -1e30f;
  lsum[0] = lsum[1] = 0.f;
  const int nsteps = t + 1;

  auto do_step = [&](int s, auto DIAGC) {
    constexpr bool DIAG = DIAGC.value;
    const int j0 = s * 64;
    __syncthreads();                              // Ks ready (drains stage vmcnt)

    floatx4 sc[2][4];
#pragma unroll
    for (int mt = 0; mt < 2; ++mt)
#pragma unroll
      for (int nt = 0; nt < 4; ++nt) sc[mt][nt] = floatx4{0.f, 0.f, 0.f, 0.f};
    __builtin_amdgcn_s_setprio(1);
#pragma unroll
    for (int nt = 0; nt < 4; ++nt) {
      short8 kf[4];
#pragma unroll
      for (int kd = 0; kd < 4; ++kd)
        kf[kd] = *(const short8*)&Ks[nt * 16 + l15][((kd * 4 + quad) ^ l15) * 8];
#pragma unroll
      for (int mt = 0; mt < 2; ++mt)
#pragma unroll
        for (int kd = 0; kd < 4; ++kd)
          sc[mt][nt] = __builtin_amdgcn_mfma_f32_16x16x32_bf16(kf[kd], qf[mt][kd], sc[mt][nt], 0, 0, 0);
    }
    __builtin_amdgcn_s_setprio(0);
    __syncthreads();                              // all waves done reading Ks
    if (!DIAG) stage(j0 + 64);                    // non-diag steps always have a successor

    short8 vf0[8];
#pragma unroll
    for (int t8 = 0; t8 < 8; ++t8)
      vf0[t8] = *(const short8*)(Vu + (size_t)(t8 * 16 + l15) * S_LEN + j0 + quad * 8);

#pragma unroll
    for (int mt = 0; mt < 2; ++mt) {
      const int qloc = wave * 32 + mt * 16 + l15;
      float pv[16];
      float vmloc = -1e30f;
#pragma unroll
      for (int nt = 0; nt < 4; ++nt)
#pragma unroll
        for (int r = 0; r < 4; ++r) {
          float x = sc[mt][nt][r];
          if (DIAG && (nt * 16 + quad * 4 + r > qloc)) x = -1e30f;
          pv[nt * 4 + r] = x;
          vmloc = fmaxf(vmloc, x);
        }
      float ps = 0.f;
      ushort pk[16];
#pragma unroll
      for (int i = 0; i < 16; ++i) {               // speculative: old running max
        float p = __expf(pv[i] - mst[mt]);
        ps += p;
        pk[i] = f2bu(p);
      }
      if (__any(vmloc > mst[mt] + 8.0f)) {         // per-lane predicate; ballot covers row
        float vm = fmaxf(vmloc, __shfl_xor(vmloc, 16));
        vm = fmaxf(vm, __shfl_xor(vm, 32));
        const float mnew = fmaxf(mst[mt], vm);
        const float al = __expf(mst[mt] - mnew);
        mst[mt] = mnew;
        lsum[mt] *= al;
        ps = 0.f;
#pragma unroll
        for (int i = 0; i < 16; ++i) {
          float p = __expf(pv[i] - mst[mt]);
          ps += p;
          pk[i] = f2bu(p);
        }
        float ar[4];
#pragma unroll
        for (int r = 0; r < 4; ++r)
          ar[r] = __shfl(al, (lane & 48) | (quad * 4 + r));
#pragma unroll
        for (int t8 = 0; t8 < 8; ++t8)
#pragma unroll
          for (int r = 0; r < 4; ++r) o[mt][t8][r] *= ar[r];
      }
      lsum[mt] += ps;
#pragma unroll
      for (int nt = 0; nt < 4; ++nt) {
        ushort4 w;
        w.x = pk[nt * 4 + 0]; w.y = pk[nt * 4 + 1];
        w.z = pk[nt * 4 + 2]; w.w = pk[nt * 4 + 3];
        *(ushort4*)&P[wave][mt * 16 + l15][nt * 16 + quad * 4] = w;
      }
    }

    short8 vf1[8];
#pragma unroll
    for (int t8 = 0; t8 < 8; ++t8)
      vf1[t8] = *(const short8*)(Vu + (size_t)(t8 * 16 + l15) * S_LEN + j0 + 32 + quad * 8);

    asm volatile("s_waitcnt lgkmcnt(0)" ::: "memory");
    short8 pf[2][2];
#pragma unroll
    for (int mt = 0; mt < 2; ++mt)
#pragma unroll
      for (int hh = 0; hh < 2; ++hh)
        pf[mt][hh] = *(const short8*)&P[wave][mt * 16 + l15][hh * 32 + quad * 8];
    __builtin_amdgcn_s_setprio(1);
#pragma unroll
    for (int t8 = 0; t8 < 8; ++t8)
#pragma unroll
      for (int mt = 0; mt < 2; ++mt) {
        o[mt][t8] = __builtin_amdgcn_mfma_f32_16x16x32_bf16(pf[mt][0], vf0[t8], o[mt][t8], 0, 0, 0);
        o[mt][t8] = __builtin_amdgcn_mfma_f32_16x16x32_bf16(pf[mt][1], vf1[t8], o[mt][t8], 0, 0, 0);
      }
    __builtin_amdgcn_s_setprio(0);
  };

  stage(0);
  for (int s = 0; s < t; ++s) do_step(s, std::integral_constant<bool, false>{});
  do_step(t, std::integral_constant<bool, true>{});

#pragma unroll
  for (int mt = 0; mt < 2; ++mt) {
    float ls = lsum[mt];
    ls += __shfl_xor(ls, 16);
    ls += __shfl_xor(ls, 32);
    float inv[4];
#pragma unroll
    for (int r = 0; r < 4; ++r)
      inv[r] = 1.0f / __shfl(ls, (lane & 48) | (quad * 4 + r));
#pragma unroll
    for (int r = 0; r < 4; ++r) {
      const int row = q0 + mt * 16 + quad * 4 + r;
#pragma unroll
      for (int t8 = 0; t8 < 8; ++t8)
        AO[(size_t)row * HID + head * HD + t8 * 16 + l15] = __float2bfloat16(o[mt][t8][r] * inv[r]);
    }
  }
}

extern "C" void kernel_launch(void* const* d_in, const int* in_sizes, int n_in,
                              void* d_out, int out_size, void* d_ws, size_t ws_size,
                              hipStream_t stream) {
  const float* x    = (const float*)d_in[0];
  const float* wq   = (const float*)d_in[1];
  const float* wk   = (const float*)d_in[2];
  const float* wv   = (const float*)d_in[3];
  const float* wo   = (const float*)d_in[4];
  const float* cosp = (const float*)d_in[5];
  const float* sinp = (const float*)d_in[6];
  float* out = (float*)d_out;

  char* ws = (char*)d_ws;
  size_t off = 0;
  auto alloc = [&](size_t bytes) { char* p = ws + off; off += (bytes + 255) & ~255ull; return p; };
  __hip_bfloat16* Xb   = (__hip_bfloat16*)alloc((size_t)S_LEN * KDIM * 2);
  __hip_bfloat16* Wqkv = (__hip_bfloat16*)alloc((size_t)QKV_N * KDIM * 2);
  __hip_bfloat16* Wob  = (__hip_bfloat16*)alloc((size_t)HID * HID * 2);
  __hip_bfloat16* QKVb = (__hip_bfloat16*)alloc((size_t)S_LEN * QKV_N * 2);
  __hip_bfloat16* Qh   = (__hip_bfloat16*)alloc((size_t)NH * S_LEN * HD * 2);
  __hip_bfloat16* Kh   = (__hip_bfloat16*)alloc((size_t)NKV * S_LEN * HD * 2);
  __hip_bfloat16* Vt   = (__hip_bfloat16*)alloc((size_t)NKV * HD * S_LEN * 2);
  __hip_bfloat16* AO   = (__hip_bfloat16*)alloc((size_t)S_LEN * HID * 2);

  cvt_all<<<dim3(3072), dim3(256), 0, stream>>>(x, wq, wk, wv, wo, Xb, Wqkv, Wob);

  gemm_nt<__hip_bfloat16><<<dim3(QKV_N / 128, S_LEN / 128), dim3(256), 0, stream>>>(
      Xb, Wqkv, QKVb, S_LEN, QKV_N, KDIM);
  rope_qk<<<dim3((S_LEN * 40 * 8) / 256), dim3(256), 0, stream>>>(QKVb, cosp, sinp, Qh, Kh);
  v_transpose<<<dim3(S_LEN / 64, NKV), dim3(256), 0, stream>>>(QKVb, Vt);
  attn<<<dim3(1024), dim3(128), 0, stream>>>(Qh, Kh, Vt, AO);
  gemm_nt<float><<<dim3(HID / 128, S_LEN / 128), dim3(256), 0, stream>>>(
      AO, Wob, out, S_LEN, HID, KDIM);
}